// Round 3
// baseline (551.974 us; speedup 1.0000x reference)
//
#include <hip/hip_runtime.h>
#include <hip/hip_bf16.h>
#include <math.h>

#define BATCH 512
#define FEAT 512
#define NCLS 1000
#define MSZ 200
#define KP 50
#define KN 20
#define INV_TEMP (1.0f/0.07f)
#define MARGIN 0.5f
#define NBROWS 20096          // NCLS*KN (=20000) padded to multiple of 128
#define NCB 157               // col blocks of 128
#define NPART (NCB*2)         // partials per row: colblock x wave-col

typedef __attribute__((ext_vector_type(8))) short short8;
typedef __attribute__((ext_vector_type(4))) float f32x4;

__device__ __forceinline__ unsigned short f2bf(float x) {
    __hip_bfloat16 h = __float2bfloat16(x);   // RNE
    return *reinterpret_cast<unsigned short*>(&h);
}

__device__ __forceinline__ void gload_lds16(const void* g, void* l) {
    __builtin_amdgcn_global_load_lds(
        (const __attribute__((address_space(1))) void*)g,
        (__attribute__((address_space(3))) void*)l, 16, 0, 0);
}

// ---------------- K0: init ov = -1, own_sum = 0, out = 0 ----------------
__global__ void k_init(int* __restrict__ ov, float* __restrict__ own_sum,
                       float* __restrict__ out) {
    int i = blockIdx.x * blockDim.x + threadIdx.x;
    if (i < NCLS * KP) ov[i] = -1;
    if (i < BATCH) own_sum[i] = 0.f;
    if (i == 0) out[0] = 0.f;
}

// ---------------- K1: L2-normalize -> f (fp32) + fb (bf16, chunk-swizzled) --------
// Swizzle: within each 128-B group of a row, logical 16-B chunk c is stored at
// chunk position c ^ (row & 7). global_load_lds then lands it so that the MFMA
// fragment read (quad q, row r -> chunk q^(r&7)) is bank-uniform.
__global__ void k_norm(const float* __restrict__ x, float* __restrict__ f,
                       unsigned short* __restrict__ fb) {
    int row = blockIdx.x;
    int t = threadIdx.x;  // 128 threads, float4 (16B logical bytes t*8..)
    float4 v = ((const float4*)(x + (size_t)row * FEAT))[t];
    float ss = v.x*v.x + v.y*v.y + v.z*v.z + v.w*v.w;
    for (int off = 32; off; off >>= 1) ss += __shfl_down(ss, off);
    __shared__ float w[2];
    if ((t & 63) == 0) w[t >> 6] = ss;
    __syncthreads();
    float inv = 1.f / fmaxf(sqrtf(w[0] + w[1]), 1e-12f);
    float4 o; o.x = v.x*inv; o.y = v.y*inv; o.z = v.z*inv; o.w = v.w*inv;
    ((float4*)(f + (size_t)row * FEAT))[t] = o;
    unsigned long long pk = (unsigned long long)f2bf(o.x)
                          | ((unsigned long long)f2bf(o.y) << 16)
                          | ((unsigned long long)f2bf(o.z) << 32)
                          | ((unsigned long long)f2bf(o.w) << 48);
    int group = t >> 4;            // 128-B group (8 B per thread, 16 threads/group)
    int chunk = (t >> 1) & 7;      // 16-B chunk within group
    int off8  = (t & 1) * 4;       // ushort offset within chunk
    int idx = group * 64 + ((chunk ^ (row & 7)) * 8) + off8;
    *(unsigned long long*)(fb + (size_t)row * FEAT + idx) = pk;
}

// ---------------- K2: rank / group_size / first_idx / override table ----------------
__global__ void k_meta(const int* __restrict__ labels, const int* __restrict__ mptr,
                       int* __restrict__ rank, int* __restrict__ gs,
                       int* __restrict__ fidx, int* __restrict__ ov) {
    __shared__ int lab[BATCH];
    int i = threadIdx.x;
    lab[i] = labels[i];
    __syncthreads();
    int l = lab[i];
    int r = 0, cnt = 0, first = -1;
    for (int j = 0; j < BATCH; j++) {
        if (lab[j] == l) { if (j < i) r++; cnt++; if (first < 0) first = j; }
    }
    rank[i] = r; gs[i] = cnt; fidx[i] = first;
    int wp = (mptr[l] + r) % MSZ;
    if (wp < KP) ov[l * KP + wp] = i;
}

// ---------------- K3: build Bm (bf16, overridden bank[:, :KN], chunk-swizzled) ------
__global__ __launch_bounds__(256) void k_conv(const float* __restrict__ f,
                                              const float* __restrict__ bank,
                                              const int* __restrict__ ov,
                                              unsigned short* __restrict__ Bm) {
    int g = blockIdx.x * 4 + (threadIdx.x >> 6);   // one wave per row
    int lane = threadIdx.x & 63;
    int group = lane >> 3, chunk = lane & 7;
    unsigned short* dst = Bm + (size_t)g * FEAT
                        + group * 64 + ((chunk ^ (g & 7)) * 8);
    if (g >= NCLS * KN) {
        short8 z = {0,0,0,0,0,0,0,0};
        *(short8*)dst = z;
        return;
    }
    int c = g / KN, s = g - c * KN;
    int o = ov[c * KP + s];
    const float* src = (o >= 0) ? (f + (size_t)o * FEAT)
                                : (bank + ((size_t)c * MSZ + s) * FEAT);
    const float4* s4 = (const float4*)(src + lane * 8);
    float4 v0 = s4[0], v1 = s4[1];
    short8 out;
    out[0] = (short)f2bf(v0.x); out[1] = (short)f2bf(v0.y);
    out[2] = (short)f2bf(v0.z); out[3] = (short)f2bf(v0.w);
    out[4] = (short)f2bf(v1.x); out[5] = (short)f2bf(v1.y);
    out[6] = (short)f2bf(v1.z); out[7] = (short)f2bf(v1.w);
    *(short8*)dst = out;
}

// ---------------- K4: batch positives + own-class slots KN..KP-1 (fp32, exact) -----
__global__ __launch_bounds__(256) void k_pos(
    const float* __restrict__ f, const int* __restrict__ labels,
    const int* __restrict__ rank, const int* __restrict__ gs,
    const int* __restrict__ fidx, const int* __restrict__ ov,
    const float* __restrict__ bank,
    float* __restrict__ psb, float* __restrict__ cb, float* __restrict__ own2)
{
    int i = blockIdx.x;
    int t = threadIdx.x, w = t >> 6, lane = t & 63;
    __shared__ float fi[FEAT];
    for (int d = t; d < FEAT; d += 256) fi[d] = f[(size_t)i * FEAT + d];
    __syncthreads();
    int li = labels[i], fi_first = fidx[i], gsi = gs[i];

    // part 1: in-batch positives
    float s = 0.f, c = 0.f;
    if (gsi > 1) {
        for (int j = t; j < BATCH; j += 256) {
            if (labels[j] == li && rank[j] != fi_first) {
                const float4* fj = (const float4*)(f + (size_t)j * FEAT);
                float acc = 0.f;
                #pragma unroll 8
                for (int d = 0; d < FEAT / 4; d++) {
                    float4 a = ((const float4*)fi)[d];
                    float4 b = fj[d];
                    acc += a.x*b.x + a.y*b.y + a.z*b.z + a.w*b.w;
                }
                s += acc * INV_TEMP;
                c += 1.f;
            }
        }
    }
    // part 2: own-class memory slots KN..KP-1
    float a0=0,a1=0,a2=0,a3=0,a4=0,a5=0,a6=0,a7=0;
    for (int sl = KN + w; sl < KP; sl += 4) {
        int o = ov[li * KP + sl];
        const float* src = (o >= 0) ? (f + (size_t)o * FEAT)
                                    : (bank + ((size_t)li * MSZ + sl) * FEAT);
        const float4* s4 = (const float4*)(src + lane * 8);
        float4 v0 = s4[0], v1 = s4[1];
        a0 += v0.x; a1 += v0.y; a2 += v0.z; a3 += v0.w;
        a4 += v1.x; a5 += v1.y; a6 += v1.z; a7 += v1.w;
    }
    const float4* f4 = (const float4*)(fi + lane * 8);
    float4 fa = f4[0], fbv = f4[1];
    float p = fa.x*a0 + fa.y*a1 + fa.z*a2 + fa.w*a3
            + fbv.x*a4 + fbv.y*a5 + fbv.z*a6 + fbv.w*a7;

    for (int off = 32; off; off >>= 1) {
        s += __shfl_down(s, off); c += __shfl_down(c, off); p += __shfl_down(p, off);
    }
    __shared__ float ws[4], wc[4], wp[4];
    if (lane == 0) { ws[w] = s; wc[w] = c; wp[w] = p; }
    __syncthreads();
    if (t == 0) {
        psb[i]  = ws[0] + ws[1] + ws[2] + ws[3];
        cb[i]   = wc[0] + wc[1] + wc[2] + wc[3];
        own2[i] = (wp[0] + wp[1] + wp[2] + wp[3]) * INV_TEMP;
    }
}

// ---------------- K5: bf16 MFMA GEMM 512 x NBROWS x 512, fused epilogue ----------------
// Tile 128 rows x 128 cols, BK=64. 4 waves 2x2 (wr,wc), each 64x64 = 4x4 frags.
#define BK 64
__global__ __launch_bounds__(256) void k_main(
    const unsigned short* __restrict__ fb, const unsigned short* __restrict__ Bm,
    const int* __restrict__ labels,
    float* __restrict__ own_sum,
    float* __restrict__ pa_all, float* __restrict__ pa_hs, float* __restrict__ pa_hc)
{
    int cbk = blockIdx.y;
    int rbase = blockIdx.x * 128;
    int t = threadIdx.x;
    int w = t >> 6, lane = t & 63;
    int wr = w >> 1, wc = w & 1;
    int ln15 = lane & 15, quad = lane >> 4;

    __shared__ __align__(16) unsigned short As[128 * BK];  // 16 KB (swizzled chunks)
    __shared__ __align__(16) unsigned short Bs[128 * BK];  // 16 KB

    f32x4 acc[4][4];
    #pragma unroll
    for (int i = 0; i < 4; i++)
        #pragma unroll
        for (int j = 0; j < 4; j++) acc[i][j] = (f32x4){0.f, 0.f, 0.f, 0.f};

    const char* aSrc[4]; void* aDst[4];
    const char* bSrc[4]; void* bDst[4];
    #pragma unroll
    for (int q = 0; q < 4; q++) {
        unsigned int L = q * 4096 + w * 1024 + lane * 16;
        int row = L >> 7;                 // 128 B per LDS row (BK=64 bf16)
        int part = L & 127;
        aSrc[q] = (const char*)fb + (size_t)(rbase + row) * (FEAT * 2) + part;
        aDst[q] = (char*)As + (q * 4096 + w * 1024);
        bSrc[q] = (const char*)Bm + (size_t)(cbk * 128 + row) * (FEAT * 2) + part;
        bDst[q] = (char*)Bs + (q * 4096 + w * 1024);
    }

    for (int k0 = 0; k0 < FEAT; k0 += BK) {
        __syncthreads();  // previous chunk's ds_reads done
        #pragma unroll
        for (int q = 0; q < 4; q++) gload_lds16(aSrc[q] + k0 * 2, aDst[q]);
        #pragma unroll
        for (int q = 0; q < 4; q++) gload_lds16(bSrc[q] + k0 * 2, bDst[q]);
        __syncthreads();  // drain DMA

        #pragma unroll
        for (int kh = 0; kh < BK; kh += 32) {
            int ch = (kh >> 3) + quad;    // logical 16-B chunk 0..7
            short8 a[4], b[4];
            #pragma unroll
            for (int i = 0; i < 4; i++) {
                int ri = wr * 64 + i * 16 + ln15;
                a[i] = *(const short8*)&As[ri * 64 + ((ch ^ (ri & 7)) * 8)];
            }
            #pragma unroll
            for (int j = 0; j < 4; j++) {
                int rj = wc * 64 + j * 16 + ln15;
                b[j] = *(const short8*)&Bs[rj * 64 + ((ch ^ (rj & 7)) * 8)];
            }
            #pragma unroll
            for (int i = 0; i < 4; i++)
                #pragma unroll
                for (int j = 0; j < 4; j++)
                    acc[i][j] = __builtin_amdgcn_mfma_f32_16x16x32_bf16(a[i], b[j], acc[i][j], 0, 0, 0);
        }
    }

    // epilogue: C/D map col=lane&15, row=quad*4+reg
    #pragma unroll
    for (int i = 0; i < 4; i++) {
        #pragma unroll
        for (int r = 0; r < 4; r++) {
            int grow = rbase + wr * 64 + i * 16 + quad * 4 + r;
            int lab = labels[grow];
            float own = 0.f, alls = 0.f, hs = 0.f, hc = 0.f;
            #pragma unroll
            for (int j = 0; j < 4; j++) {
                int gcol = cbk * 128 + wc * 64 + j * 16 + ln15;
                float sim = acc[i][j][r] * INV_TEMP;
                if (gcol < NCLS * KN) {
                    int c = gcol / KN;
                    if (c == lab) {
                        own += sim;
                    } else {
                        alls += sim;
                        if (sim > MARGIN) { hs += sim; hc += 1.f; }
                    }
                }
            }
            #pragma unroll
            for (int off = 8; off; off >>= 1) {
                own  += __shfl_down(own,  off, 16);
                alls += __shfl_down(alls, off, 16);
                hs   += __shfl_down(hs,   off, 16);
                hc   += __shfl_down(hc,   off, 16);
            }
            if (ln15 == 0) {
                size_t pidx = (size_t)(cbk * 2 + wc) * BATCH + grow;
                pa_all[pidx] = alls; pa_hs[pidx] = hs; pa_hc[pidx] = hc;
                if (own != 0.f) atomicAdd(&own_sum[grow], own);
            }
        }
    }
}

// ---------------- K6: reduce partials + per-row loss + mean (one atomic/row) ------
__global__ void k_tail(const float* __restrict__ pa_all, const float* __restrict__ pa_hs,
                       const float* __restrict__ pa_hc,
                       const float* __restrict__ own_sum, const float* __restrict__ own2,
                       const float* __restrict__ psb, const float* __restrict__ cb,
                       float* __restrict__ out)
{
    int row = blockIdx.x;
    int t = threadIdx.x;  // 256
    float a = 0.f, h = 0.f, hc = 0.f;
    for (int p = t; p < NPART; p += 256) {
        size_t idx = (size_t)p * BATCH + row;
        a += pa_all[idx]; h += pa_hs[idx]; hc += pa_hc[idx];
    }
    for (int off = 32; off; off >>= 1) {
        a += __shfl_down(a, off); h += __shfl_down(h, off); hc += __shfl_down(hc, off);
    }
    __shared__ float wa[4], wh[4], wcn[4];
    int w = t >> 6, lane = t & 63;
    if (lane == 0) { wa[w] = a; wh[w] = h; wcn[w] = hc; }
    __syncthreads();
    if (t == 0) {
        float alls = wa[0] + wa[1] + wa[2] + wa[3];
        float hsum = wh[0] + wh[1] + wh[2] + wh[3];
        float hcnt = wcn[0] + wcn[1] + wcn[2] + wcn[3];
        float pos = -(psb[row] + own_sum[row] + own2[row]) / (cb[row] + (float)KP);
        float neg = (hcnt > 0.f) ? hsum / fmaxf(hcnt, 1.f)
                                 : alls / ((float)(NCLS - 1) * (float)KN);
        atomicAdd(out, (pos + neg) * (1.f / (float)BATCH));
    }
}

extern "C" void kernel_launch(void* const* d_in, const int* in_sizes, int n_in,
                              void* d_out, int out_size, void* d_ws, size_t ws_size,
                              hipStream_t stream) {
    const float* features = (const float*)d_in[0];
    const int*   labels   = (const int*)d_in[1];
    const float* bank     = (const float*)d_in[2];
    const int*   mptr     = (const int*)d_in[3];
    float* out = (float*)d_out;

    // ws layout (all 16B-aligned)
    float* f            = (float*)d_ws;                         // 512*512 f32
    unsigned short* fb  = (unsigned short*)(f + BATCH * FEAT);  // 512*512 bf16 (swizzled)
    unsigned short* Bm  = fb + (size_t)BATCH * FEAT;            // NBROWS*512 bf16 (swizzled)
    int*   ov           = (int*)(Bm + (size_t)NBROWS * FEAT);   // 1000*50
    int*   rank         = ov + NCLS * KP;                       // 512
    int*   gs           = rank + BATCH;
    int*   fidx         = gs + BATCH;
    float* own_sum      = (float*)(fidx + BATCH);
    float* own2         = own_sum + BATCH;
    float* psb          = own2 + BATCH;
    float* cb           = psb + BATCH;
    float* pa_all       = cb + BATCH;                           // NPART*512 each
    float* pa_hs        = pa_all + (size_t)NPART * BATCH;
    float* pa_hc        = pa_hs + (size_t)NPART * BATCH;

    k_init<<<(NCLS * KP + 255) / 256, 256, 0, stream>>>(ov, own_sum, out);
    k_norm<<<BATCH, 128, 0, stream>>>(features, f, fb);
    k_meta<<<1, BATCH, 0, stream>>>(labels, mptr, rank, gs, fidx, ov);
    k_conv<<<NBROWS / 4, 256, 0, stream>>>(f, bank, ov, Bm);
    k_pos<<<BATCH, 256, 0, stream>>>(f, labels, rank, gs, fidx, ov, bank, psb, cb, own2);
    dim3 g5(BATCH / 128, NCB);
    k_main<<<g5, 256, 0, stream>>>(fb, Bm, labels, own_sum, pa_all, pa_hs, pa_hc);
    k_tail<<<BATCH, 256, 0, stream>>>(pa_all, pa_hs, pa_hc, own_sum, own2, psb, cb, out);
}